// Round 11
// baseline (189.717 us; speedup 1.0000x reference)
//
#include <hip/hip_runtime.h>

#define NIN   784
#define NOUT  512
#define NROWS 785      // NIN + 1 (bias row)
#define BATCH 256
#define CHUNK 10       // i-rows per block
#define NZ    80       // 80*10 = 800 >= 785; grid 4*4*80 = 1280 = 5 blocks/CU
#define JTILE 128      // columns per block
#define BTILE 64       // batches per block

static constexpr float G_MIN_F  = (float)(1.0 / 983.3);
static constexpr float G_DIFF_F = (float)(1.0 / 281.3 - 1.0 / 983.3);

// device fast transcendental: v_log_f32 (log2), v_exp_f32 (2^x)
__device__ __forceinline__ float dlog2(float v) { return __builtin_amdgcn_logf(v); }
__device__ __forceinline__ float dexp2(float v) { return __builtin_amdgcn_exp2f(v); }

// 256-thread-block reduce of the 128 partial maxima (all threads return max).
__device__ __forceinline__ float load_maxw(const float* __restrict__ pm, int tid) {
    float m = pm[tid & 127];
    #pragma unroll
    for (int off = 1; off < 64; off <<= 1)
        m = fmaxf(m, __shfl_xor(m, off, 64));
    __shared__ float sm2[4];
    if ((tid & 63) == 0) sm2[tid >> 6] = m;
    __syncthreads();
    return fmaxf(fmaxf(sm2[0], sm2[1]), fmaxf(sm2[2], sm2[3]));
}

// ---------------------------------------------------------------------------
// Kernel 1: per-block partial max over |weights| (vectorized) + zero d_out.
// ---------------------------------------------------------------------------
__global__ __launch_bounds__(256) void mk_max(
    const float* __restrict__ wp, const float* __restrict__ wn,
    const float* __restrict__ bp, const float* __restrict__ bn,
    float* __restrict__ part, float4* __restrict__ out4)
{
    const int gid = blockIdx.x * 256 + threadIdx.x;
    out4[gid] = make_float4(0.f, 0.f, 0.f, 0.f);

    float m = 0.0f;
    const int n4 = NIN * NOUT / 4;
    const float4* wp4 = (const float4*)wp;
    const float4* wn4 = (const float4*)wn;
    for (int idx = gid; idx < n4; idx += gridDim.x * 256) {
        float4 a = wp4[idx], b = wn4[idx];
        m = fmaxf(m, fmaxf(fmaxf(fabsf(a.x), fabsf(a.y)), fmaxf(fabsf(a.z), fabsf(a.w))));
        m = fmaxf(m, fmaxf(fmaxf(fabsf(b.x), fabsf(b.y)), fmaxf(fabsf(b.z), fabsf(b.w))));
    }
    if (blockIdx.x == 0 && threadIdx.x < NOUT) {
        m = fmaxf(m, fabsf(bp[threadIdx.x]));
        m = fmaxf(m, fabsf(bn[threadIdx.x]));
    }
    #pragma unroll
    for (int off = 1; off < 64; off <<= 1)
        m = fmaxf(m, __shfl_xor(m, off, 64));
    __shared__ float sm[4];
    if ((threadIdx.x & 63) == 0) sm[threadIdx.x >> 6] = m;
    __syncthreads();
    if (threadIdx.x == 0)
        part[blockIdx.x] = fmaxf(fmaxf(sm[0], sm[1]), fmaxf(sm[2], sm[3]));
}

// ---------------------------------------------------------------------------
// Kernel 2: fused table+crossbar, register-blocked 4 cols x 8 batches/thread.
// y[b,j] = C * sum_i s[b,i] * ( 2^(ep*L + lgGp) - 2^(en*L + lgGn) )
// Block tile: 128 cols x 64 batches x 10 i-rows; 256 thr = 32 jt x 8 bt.
// Per step/thread: 8 ds_read_b128 (96 LDS-cy) feeding 64 exp2 (512 trans-cy)
// -> trans-pipe-bound at >=2 waves/SIMD. Table in LDS as SoA floats so the
// per-thread 4-col slice is one aligned b128 with uniform bank spread.
// LDS 25.6KB -> 6 blocks/CU; grid 1280 = 5 blocks/CU exactly (no tail).
// ---------------------------------------------------------------------------
__global__ __launch_bounds__(256) void mk_main(
    const float* __restrict__ x,  const float* __restrict__ wp,
    const float* __restrict__ wn, const float* __restrict__ bp,
    const float* __restrict__ bn, const float* __restrict__ npar,
    const float* __restrict__ pm, float* __restrict__ out)
{
    const int tid = threadIdx.x;
    const float maxw = load_maxw(pm, tid);
    const float kG = G_DIFF_F / maxw;
    const float C  = 0.5f * maxw / G_DIFF_F;    // 0.5/kG

    const int jt = tid & 31;        // col-group: cols j0 + jt*4 .. +3
    const int bt = tid >> 5;        // batch-group: batches b0 + bt*8 .. +7
    const int j0 = blockIdx.x * JTILE;
    const int b0 = blockIdx.y * BTILE;
    const int i0 = blockIdx.z * CHUNK;

    __shared__ float Tep[CHUNK * JTILE], Tgp[CHUNK * JTILE];
    __shared__ float Ten[CHUNK * JTILE], Tgn[CHUNK * JTILE];
    __shared__ float Lx[CHUNK * BTILE], Sx[CHUNK * BTILE];

    // --- stage table slice (SoA): 1280 entries, 5 per thread, coalesced ---
    #pragma unroll
    for (int k = 0; k < 5; ++k) {
        const int p  = tid + k * 256;
        const int ii = p >> 7, jj = p & 127;
        const int i  = i0 + ii;
        float ep = 0.f, gp = 0.f, en = 0.f, gn = 0.f;
        if (i < NROWS) {
            const float wpv = (i < NIN) ? wp[i * NOUT + j0 + jj] : bp[j0 + jj];
            const float wnv = (i < NIN) ? wn[i * NOUT + j0 + jj] : bn[j0 + jj];
            const float2 nv = *(const float2*)(&npar[i * (2 * NOUT) + 2 * (j0 + jj)]);
            ep = dlog2(nv.x);
            gp = dlog2(fmaf(kG, fmaxf(wpv, 0.0f), G_MIN_F));
            en = dlog2(nv.y);
            gn = dlog2(fmaf(kG, fmaxf(wnv, 0.0f), G_MIN_F));
        }
        Tep[p] = ep; Tgp[p] = gp; Ten[p] = en; Tgn[p] = gn;
    }

    // --- stage {L=log2(2|x|), s=sign}: 640 entries ---
    for (int p = tid; p < CHUNK * BTILE; p += 256) {
        const int ii = p >> 6, bb = p & 63;
        const int i  = i0 + ii;
        float L = 0.0f, s = 0.0f;
        if (i < NIN) {
            const float v = x[(b0 + bb) * NIN + i];
            s = (v > 0.0f) ? 1.0f : ((v < 0.0f) ? -1.0f : 0.0f);
            L = dlog2(2.0f * fabsf(v));
        } else if (i == NIN) { L = 1.0f; s = 1.0f; }   // bias input v=1
        Lx[p] = L; Sx[p] = s;
    }
    __syncthreads();

    float acc[4][8];
    #pragma unroll
    for (int c = 0; c < 4; ++c)
        #pragma unroll
        for (int b = 0; b < 8; ++b) acc[c][b] = 0.0f;

    #pragma unroll 2
    for (int ii = 0; ii < CHUNK; ++ii) {
        const float4 ep4 = *(const float4*)&Tep[ii * JTILE + jt * 4];
        const float4 gp4 = *(const float4*)&Tgp[ii * JTILE + jt * 4];
        const float4 en4 = *(const float4*)&Ten[ii * JTILE + jt * 4];
        const float4 gn4 = *(const float4*)&Tgn[ii * JTILE + jt * 4];
        float Lb[8], Sb[8];
        *(float4*)&Lb[0] = *(const float4*)&Lx[ii * BTILE + bt * 8];
        *(float4*)&Lb[4] = *(const float4*)&Lx[ii * BTILE + bt * 8 + 4];
        *(float4*)&Sb[0] = *(const float4*)&Sx[ii * BTILE + bt * 8];
        *(float4*)&Sb[4] = *(const float4*)&Sx[ii * BTILE + bt * 8 + 4];

        const float epc[4] = {ep4.x, ep4.y, ep4.z, ep4.w};
        const float gpc[4] = {gp4.x, gp4.y, gp4.z, gp4.w};
        const float enc[4] = {en4.x, en4.y, en4.z, en4.w};
        const float gnc[4] = {gn4.x, gn4.y, gn4.z, gn4.w};
        #pragma unroll
        for (int c = 0; c < 4; ++c) {
            #pragma unroll
            for (int b = 0; b < 8; ++b) {
                const float tp = dexp2(fmaf(epc[c], Lb[b], gpc[c]));
                const float tn = dexp2(fmaf(enc[c], Lb[b], gnc[c]));
                acc[c][b] = fmaf(Sb[b], tp - tn, acc[c][b]);
            }
        }
    }

    #pragma unroll
    for (int b = 0; b < 8; ++b)
        #pragma unroll
        for (int c = 0; c < 4; ++c)
            unsafeAtomicAdd(&out[(b0 + bt * 8 + b) * NOUT + j0 + jt * 4 + c],
                            C * acc[c][b]);
}

extern "C" void kernel_launch(void* const* d_in, const int* in_sizes, int n_in,
                              void* d_out, int out_size, void* d_ws, size_t ws_size,
                              hipStream_t stream) {
    const float* x    = (const float*)d_in[0];
    const float* wp   = (const float*)d_in[1];
    const float* wn   = (const float*)d_in[2];
    const float* bp   = (const float*)d_in[3];
    const float* bn   = (const float*)d_in[4];
    const float* npar = (const float*)d_in[5];
    float*        out = (float*)d_out;
    float*         pm = (float*)d_ws;           // 128 partial maxima

    // mk_max zeroes d_out (atomic target) and writes 128 partial maxima
    mk_max<<<128, 256, 0, stream>>>(wp, wn, bp, bn, pm, (float4*)out);

    dim3 grid(NOUT / JTILE, BATCH / BTILE, NZ);
    mk_main<<<grid, 256, 0, stream>>>(x, wp, wn, bp, bn, npar, pm, out);
}

// Round 12
// 49.050 us; speedup vs baseline: 3.8679x; 3.8679x over previous
//
#include <hip/hip_runtime.h>

#define NIN   784
#define NOUT  512
#define NROWS 785      // NIN + 1 (bias row)
#define BATCH 256
#define CHUNK 20       // i-rows per block
#define NZ    40       // 40*20 = 800 >= 785 (pad rows contribute 0)
#define JTILE 128      // columns per block
#define BTILE 64       // batches per block

static constexpr float G_MIN_F  = (float)(1.0 / 983.3);
static constexpr float G_DIFF_F = (float)(1.0 / 281.3 - 1.0 / 983.3);

// device fast transcendental: v_log_f32 (log2), v_exp_f32 (2^x)
__device__ __forceinline__ float dlog2(float v) { return __builtin_amdgcn_logf(v); }
__device__ __forceinline__ float dexp2(float v) { return __builtin_amdgcn_exp2f(v); }

// ws layout: [0]: 128 partial maxima; [4096): partials float[NZ][BATCH][NOUT]
#define WS_PM_OFF 0
#define WS_PT_OFF 4096
#define WS_TOTAL  (WS_PT_OFF + (size_t)NZ * BATCH * NOUT * 4)

// 256-thread-block reduce of the 128 partial maxima (all threads return max).
__device__ __forceinline__ float load_maxw(const float* __restrict__ pm, int tid) {
    float m = pm[tid & 127];
    #pragma unroll
    for (int off = 1; off < 64; off <<= 1)
        m = fmaxf(m, __shfl_xor(m, off, 64));
    __shared__ float sm2[4];
    if ((tid & 63) == 0) sm2[tid >> 6] = m;
    __syncthreads();
    return fmaxf(fmaxf(sm2[0], sm2[1]), fmaxf(sm2[2], sm2[3]));
}

// ---------------------------------------------------------------------------
// Kernel 1: per-block partial max over |weights| (vectorized) + zero d_out.
// (zeroing kept for the atomic fallback path; 1 store/thread, negligible)
// ---------------------------------------------------------------------------
__global__ __launch_bounds__(256) void mk_max(
    const float* __restrict__ wp, const float* __restrict__ wn,
    const float* __restrict__ bp, const float* __restrict__ bn,
    float* __restrict__ part, float4* __restrict__ out4)
{
    const int gid = blockIdx.x * 256 + threadIdx.x;
    out4[gid] = make_float4(0.f, 0.f, 0.f, 0.f);

    float m = 0.0f;
    const int n4 = NIN * NOUT / 4;
    const float4* wp4 = (const float4*)wp;
    const float4* wn4 = (const float4*)wn;
    for (int idx = gid; idx < n4; idx += gridDim.x * 256) {
        float4 a = wp4[idx], b = wn4[idx];
        m = fmaxf(m, fmaxf(fmaxf(fabsf(a.x), fabsf(a.y)), fmaxf(fabsf(a.z), fabsf(a.w))));
        m = fmaxf(m, fmaxf(fmaxf(fabsf(b.x), fabsf(b.y)), fmaxf(fabsf(b.z), fabsf(b.w))));
    }
    if (blockIdx.x == 0 && threadIdx.x < NOUT) {
        m = fmaxf(m, fabsf(bp[threadIdx.x]));
        m = fmaxf(m, fabsf(bn[threadIdx.x]));
    }
    #pragma unroll
    for (int off = 1; off < 64; off <<= 1)
        m = fmaxf(m, __shfl_xor(m, off, 64));
    __shared__ float sm[4];
    if ((threadIdx.x & 63) == 0) sm[threadIdx.x >> 6] = m;
    __syncthreads();
    if (threadIdx.x == 0)
        part[blockIdx.x] = fmaxf(fmaxf(sm[0], sm[1]), fmaxf(sm[2], sm[3]));
}

// ---------------------------------------------------------------------------
// Kernel 2: fused table+crossbar, register-blocked 4 cols x 8 batches/thread.
// Trans-bound by design: per step/thread 64 exp2 (512 trans-cy) vs 8
// ds_read_b128 (~96 LDS-cy); 4 SIMDs x 96 < 512 -> LDS pipe not the limit.
// USE_PART=true: contention-free float4 partial stores to ws[z] (no atomics).
// USE_PART=false (fallback): atomic adds scaled by C.
// Grid (4 jx, 4 by, 40 z): wgid = jx+4by+16z -> wgid%8 = (jx+4by)%8 for all
// z -> a tile's partials stay on one XCD (L2-local for the reduce).
// ---------------------------------------------------------------------------
template<bool USE_PART>
__global__ __launch_bounds__(256) void mk_main(
    const float* __restrict__ x,  const float* __restrict__ wp,
    const float* __restrict__ wn, const float* __restrict__ bp,
    const float* __restrict__ bn, const float* __restrict__ npar,
    const float* __restrict__ pm, float* __restrict__ dst)
{
    const int tid = threadIdx.x;
    const float maxw = load_maxw(pm, tid);
    const float kG = G_DIFF_F / maxw;
    const float C  = 0.5f * maxw / G_DIFF_F;    // 0.5/kG

    const int jt = tid & 31;        // col-group: cols j0 + jt*4 .. +3
    const int bt = tid >> 5;        // batch-group: batches b0 + bt*8 .. +7
    const int j0 = blockIdx.x * JTILE;
    const int b0 = blockIdx.y * BTILE;
    const int i0 = blockIdx.z * CHUNK;

    __shared__ float Tep[CHUNK * JTILE], Tgp[CHUNK * JTILE];
    __shared__ float Ten[CHUNK * JTILE], Tgn[CHUNK * JTILE];
    __shared__ float Lx[CHUNK * BTILE], Sx[CHUNK * BTILE];

    // --- stage table slice (SoA): 2560 entries, 10 per thread, coalesced ---
    #pragma unroll
    for (int k = 0; k < CHUNK * JTILE / 256; ++k) {
        const int p  = tid + k * 256;
        const int ii = p >> 7, jj = p & 127;
        const int i  = i0 + ii;
        float ep = 0.f, gp = 0.f, en = 0.f, gn = 0.f;
        if (i < NROWS) {
            const float wpv = (i < NIN) ? wp[i * NOUT + j0 + jj] : bp[j0 + jj];
            const float wnv = (i < NIN) ? wn[i * NOUT + j0 + jj] : bn[j0 + jj];
            const float2 nv = *(const float2*)(&npar[i * (2 * NOUT) + 2 * (j0 + jj)]);
            ep = dlog2(nv.x);
            gp = dlog2(fmaf(kG, fmaxf(wpv, 0.0f), G_MIN_F));
            en = dlog2(nv.y);
            gn = dlog2(fmaf(kG, fmaxf(wnv, 0.0f), G_MIN_F));
        }
        Tep[p] = ep; Tgp[p] = gp; Ten[p] = en; Tgn[p] = gn;
    }

    // --- stage {L=log2(2|x|), s=sign}: 1280 entries, 5 per thread ---
    #pragma unroll
    for (int k = 0; k < CHUNK * BTILE / 256; ++k) {
        const int p  = tid + k * 256;
        const int ii = p >> 6, bb = p & 63;
        const int i  = i0 + ii;
        float L = 0.0f, s = 0.0f;
        if (i < NIN) {
            const float v = x[(b0 + bb) * NIN + i];
            s = (v > 0.0f) ? 1.0f : ((v < 0.0f) ? -1.0f : 0.0f);
            L = dlog2(2.0f * fabsf(v));
        } else if (i == NIN) { L = 1.0f; s = 1.0f; }   // bias input v=1
        Lx[p] = L; Sx[p] = s;
    }
    __syncthreads();

    float acc[4][8];
    #pragma unroll
    for (int c = 0; c < 4; ++c)
        #pragma unroll
        for (int b = 0; b < 8; ++b) acc[c][b] = 0.0f;

    #pragma unroll 2
    for (int ii = 0; ii < CHUNK; ++ii) {
        const float4 ep4 = *(const float4*)&Tep[ii * JTILE + jt * 4];
        const float4 gp4 = *(const float4*)&Tgp[ii * JTILE + jt * 4];
        const float4 en4 = *(const float4*)&Ten[ii * JTILE + jt * 4];
        const float4 gn4 = *(const float4*)&Tgn[ii * JTILE + jt * 4];
        float Lb[8], Sb[8];
        *(float4*)&Lb[0] = *(const float4*)&Lx[ii * BTILE + bt * 8];
        *(float4*)&Lb[4] = *(const float4*)&Lx[ii * BTILE + bt * 8 + 4];
        *(float4*)&Sb[0] = *(const float4*)&Sx[ii * BTILE + bt * 8];
        *(float4*)&Sb[4] = *(const float4*)&Sx[ii * BTILE + bt * 8 + 4];

        const float epc[4] = {ep4.x, ep4.y, ep4.z, ep4.w};
        const float gpc[4] = {gp4.x, gp4.y, gp4.z, gp4.w};
        const float enc[4] = {en4.x, en4.y, en4.z, en4.w};
        const float gnc[4] = {gn4.x, gn4.y, gn4.z, gn4.w};
        #pragma unroll
        for (int c = 0; c < 4; ++c) {
            #pragma unroll
            for (int b = 0; b < 8; ++b) {
                const float tp = dexp2(fmaf(epc[c], Lb[b], gpc[c]));
                const float tn = dexp2(fmaf(enc[c], Lb[b], gnc[c]));
                acc[c][b] = fmaf(Sb[b], tp - tn, acc[c][b]);
            }
        }
    }

    if (USE_PART) {
        // contention-free: one float4 store per (batch,b) row slice
        float* base = dst + (size_t)blockIdx.z * (BATCH * NOUT);
        #pragma unroll
        for (int b = 0; b < 8; ++b) {
            float4 v = make_float4(acc[0][b], acc[1][b], acc[2][b], acc[3][b]);
            *(float4*)&base[(b0 + bt * 8 + b) * NOUT + j0 + jt * 4] = v;
        }
    } else {
        #pragma unroll
        for (int b = 0; b < 8; ++b)
            #pragma unroll
            for (int c = 0; c < 4; ++c)
                unsafeAtomicAdd(&dst[(b0 + bt * 8 + b) * NOUT + j0 + jt * 4 + c],
                                C * acc[c][b]);
    }
}

// ---------------------------------------------------------------------------
// Kernel 3: reduce NZ z-partials per output, scale by C.
// Grid 512, indexed (tile = bid%16, sub = bid/16) so wgid%8 == tile%8 ==
// the writer blocks' wgid%8 -> same-XCD L2 reads if round-robin holds.
// ---------------------------------------------------------------------------
__global__ __launch_bounds__(256) void mk_reduce(
    const float* __restrict__ part, const float* __restrict__ pm,
    float* __restrict__ out)
{
    const int tid = threadIdx.x;
    const float C = 0.5f * load_maxw(pm, tid) / G_DIFF_F;  // 0.5/kG
    const int tile = blockIdx.x & 15;        // jx + 4*by
    const int sub  = blockIdx.x >> 4;        // 0..31, 2 batches each
    const int jx   = tile & 3, by = tile >> 2;
    const int b    = by * BTILE + sub * 2 + (tid >> 7);
    const int j    = jx * JTILE + (tid & 127);
    const int g    = b * NOUT + j;

    float s = 0.0f;
    #pragma unroll
    for (int z = 0; z < NZ; ++z)
        s += part[(size_t)z * (BATCH * NOUT) + g];
    out[g] = C * s;
}

extern "C" void kernel_launch(void* const* d_in, const int* in_sizes, int n_in,
                              void* d_out, int out_size, void* d_ws, size_t ws_size,
                              hipStream_t stream) {
    const float* x    = (const float*)d_in[0];
    const float* wp   = (const float*)d_in[1];
    const float* wn   = (const float*)d_in[2];
    const float* bp   = (const float*)d_in[3];
    const float* bn   = (const float*)d_in[4];
    const float* npar = (const float*)d_in[5];
    float*        out = (float*)d_out;
    float*         pm = (float*)((char*)d_ws + WS_PM_OFF);

    // mk_max zeroes d_out (needed only for fallback) + 128 partial maxima
    mk_max<<<128, 256, 0, stream>>>(wp, wn, bp, bn, pm, (float4*)out);

    dim3 grid(NOUT / JTILE, BATCH / BTILE, NZ);
    if (ws_size >= WS_TOTAL) {
        float* part = (float*)((char*)d_ws + WS_PT_OFF);
        mk_main<true><<<grid, 256, 0, stream>>>(x, wp, wn, bp, bn, npar, pm, part);
        mk_reduce<<<512, 256, 0, stream>>>(part, pm, out);
    } else {
        mk_main<false><<<grid, 256, 0, stream>>>(x, wp, wn, bp, bn, npar, pm, out);
    }
}

// Round 13
// 42.972 us; speedup vs baseline: 4.4149x; 1.1414x over previous
//
#include <hip/hip_runtime.h>

#define NIN   784
#define NOUT  512
#define NROWS 785      // NIN + 1 (bias row)
#define BATCH 256
#define CHUNK 20       // i-rows per block
#define NZ    40       // 40*20 = 800 >= 785 (pad rows contribute 0)
#define JTILE 128      // columns per block
#define BTILE 64       // batches per block
#define TJ    (CHUNK * JTILE)          // 2560 floats per table array
#define TB    (CHUNK * BTILE)          // 1280 floats per {L,S} array

static constexpr float G_MIN_F  = (float)(1.0 / 983.3);
static constexpr float G_DIFF_F = (float)(1.0 / 281.3 - 1.0 / 983.3);

// device fast transcendental: v_log_f32 (log2), v_exp_f32 (2^x)
__device__ __forceinline__ float dlog2(float v) { return __builtin_amdgcn_logf(v); }
__device__ __forceinline__ float dexp2(float v) { return __builtin_amdgcn_exp2f(v); }

// 256-thread-block reduce of the 128 partial maxima (all threads return max).
__device__ __forceinline__ float load_maxw(const float* __restrict__ pm, int tid) {
    float m = pm[tid & 127];
    #pragma unroll
    for (int off = 1; off < 64; off <<= 1)
        m = fmaxf(m, __shfl_xor(m, off, 64));
    __shared__ float sm2[4];
    if ((tid & 63) == 0) sm2[tid >> 6] = m;
    __syncthreads();
    return fmaxf(fmaxf(sm2[0], sm2[1]), fmaxf(sm2[2], sm2[3]));
}

// ---------------------------------------------------------------------------
// Kernel 1: per-block partial max over |weights| (vectorized) + zero d_out
// (d_out must start at 0 for the atomic epilogue; 1 store/thread).
// ---------------------------------------------------------------------------
__global__ __launch_bounds__(256) void mk_max(
    const float* __restrict__ wp, const float* __restrict__ wn,
    const float* __restrict__ bp, const float* __restrict__ bn,
    float* __restrict__ part, float4* __restrict__ out4)
{
    const int gid = blockIdx.x * 256 + threadIdx.x;
    out4[gid] = make_float4(0.f, 0.f, 0.f, 0.f);

    float m = 0.0f;
    const int n4 = NIN * NOUT / 4;
    const float4* wp4 = (const float4*)wp;
    const float4* wn4 = (const float4*)wn;
    for (int idx = gid; idx < n4; idx += gridDim.x * 256) {
        float4 a = wp4[idx], b = wn4[idx];
        m = fmaxf(m, fmaxf(fmaxf(fabsf(a.x), fabsf(a.y)), fmaxf(fabsf(a.z), fabsf(a.w))));
        m = fmaxf(m, fmaxf(fmaxf(fabsf(b.x), fabsf(b.y)), fmaxf(fabsf(b.z), fabsf(b.w))));
    }
    if (blockIdx.x == 0 && threadIdx.x < NOUT) {
        m = fmaxf(m, fabsf(bp[threadIdx.x]));
        m = fmaxf(m, fabsf(bn[threadIdx.x]));
    }
    #pragma unroll
    for (int off = 1; off < 64; off <<= 1)
        m = fmaxf(m, __shfl_xor(m, off, 64));
    __shared__ float sm[4];
    if ((threadIdx.x & 63) == 0) sm[threadIdx.x >> 6] = m;
    __syncthreads();
    if (threadIdx.x == 0)
        part[blockIdx.x] = fmaxf(fmaxf(sm[0], sm[1]), fmaxf(sm[2], sm[3]));
}

// ---------------------------------------------------------------------------
// Kernel 2: fused table+crossbar, register-blocked 4 cols x 8 batches/thread.
// y[b,j] = C * sum_i s[b,i] * ( 2^(ep*L + lgGp) - 2^(en*L + lgGn) )
// Trans-bound by design: per step/thread 64 exp2 (512 trans-cy) vs 8
// ds_read_b128 (~96 LDS-cy); 4 SIMDs x 96 < 512.
// Epilogue: in-LDS transpose (reuse table LDS) -> 32 fully-coalesced scalar
// atomics per thread (each wave-instr covers 256B contiguous; 5.2M atomics
// at 40-way contention = known-good envelope, unlike R11's scattered 10.5M).
// LDS 51.2KB -> 3 blocks/CU; grid 640 -> all blocks co-resident.
// ---------------------------------------------------------------------------
__global__ __launch_bounds__(256) void mk_main(
    const float* __restrict__ x,  const float* __restrict__ wp,
    const float* __restrict__ wn, const float* __restrict__ bp,
    const float* __restrict__ bn, const float* __restrict__ npar,
    const float* __restrict__ pm, float* __restrict__ out)
{
    const int tid = threadIdx.x;
    const float maxw = load_maxw(pm, tid);
    const float kG = G_DIFF_F / maxw;
    const float C  = 0.5f * maxw / G_DIFF_F;    // 0.5/kG

    const int jt = tid & 31;        // col-group: cols j0 + jt*4 .. +3
    const int bt = tid >> 5;        // batch-group: batches b0 + bt*8 .. +7
    const int j0 = blockIdx.x * JTILE;
    const int b0 = blockIdx.y * BTILE;
    const int i0 = blockIdx.z * CHUNK;

    // one LDS pool: 4 table arrays (SoA) + Lx + Sx = 12800 floats (51.2KB);
    // epilogue reuses the first 8448 floats as a float4[64][33] scratch.
    __shared__ float B[TJ * 4 + TB * 2];
    float* Tep = B;
    float* Tgp = B + TJ;
    float* Ten = B + TJ * 2;
    float* Tgn = B + TJ * 3;
    float* Lx  = B + TJ * 4;
    float* Sx  = B + TJ * 4 + TB;

    // --- stage table slice (SoA): 2560 entries, 10 per thread, coalesced ---
    #pragma unroll
    for (int k = 0; k < TJ / 256; ++k) {
        const int p  = tid + k * 256;
        const int ii = p >> 7, jj = p & 127;
        const int i  = i0 + ii;
        float ep = 0.f, gp = 0.f, en = 0.f, gn = 0.f;
        if (i < NROWS) {
            const float wpv = (i < NIN) ? wp[i * NOUT + j0 + jj] : bp[j0 + jj];
            const float wnv = (i < NIN) ? wn[i * NOUT + j0 + jj] : bn[j0 + jj];
            const float2 nv = *(const float2*)(&npar[i * (2 * NOUT) + 2 * (j0 + jj)]);
            ep = dlog2(nv.x);
            gp = dlog2(fmaf(kG, fmaxf(wpv, 0.0f), G_MIN_F));
            en = dlog2(nv.y);
            gn = dlog2(fmaf(kG, fmaxf(wnv, 0.0f), G_MIN_F));
        }
        Tep[p] = ep; Tgp[p] = gp; Ten[p] = en; Tgn[p] = gn;
    }

    // --- stage {L=log2(2|x|), s=sign}: 1280 entries, 5 per thread ---
    #pragma unroll
    for (int k = 0; k < TB / 256; ++k) {
        const int p  = tid + k * 256;
        const int ii = p >> 6, bb = p & 63;
        const int i  = i0 + ii;
        float L = 0.0f, s = 0.0f;
        if (i < NIN) {
            const float v = x[(b0 + bb) * NIN + i];
            s = (v > 0.0f) ? 1.0f : ((v < 0.0f) ? -1.0f : 0.0f);
            L = dlog2(2.0f * fabsf(v));
        } else if (i == NIN) { L = 1.0f; s = 1.0f; }   // bias input v=1
        Lx[p] = L; Sx[p] = s;
    }
    __syncthreads();

    float acc[4][8];
    #pragma unroll
    for (int c = 0; c < 4; ++c)
        #pragma unroll
        for (int b = 0; b < 8; ++b) acc[c][b] = 0.0f;

    #pragma unroll 2
    for (int ii = 0; ii < CHUNK; ++ii) {
        const float4 ep4 = *(const float4*)&Tep[ii * JTILE + jt * 4];
        const float4 gp4 = *(const float4*)&Tgp[ii * JTILE + jt * 4];
        const float4 en4 = *(const float4*)&Ten[ii * JTILE + jt * 4];
        const float4 gn4 = *(const float4*)&Tgn[ii * JTILE + jt * 4];
        float Lb[8], Sb[8];
        *(float4*)&Lb[0] = *(const float4*)&Lx[ii * BTILE + bt * 8];
        *(float4*)&Lb[4] = *(const float4*)&Lx[ii * BTILE + bt * 8 + 4];
        *(float4*)&Sb[0] = *(const float4*)&Sx[ii * BTILE + bt * 8];
        *(float4*)&Sb[4] = *(const float4*)&Sx[ii * BTILE + bt * 8 + 4];

        const float epc[4] = {ep4.x, ep4.y, ep4.z, ep4.w};
        const float gpc[4] = {gp4.x, gp4.y, gp4.z, gp4.w};
        const float enc[4] = {en4.x, en4.y, en4.z, en4.w};
        const float gnc[4] = {gn4.x, gn4.y, gn4.z, gn4.w};
        #pragma unroll
        for (int c = 0; c < 4; ++c) {
            #pragma unroll
            for (int b = 0; b < 8; ++b) {
                const float tp = dexp2(fmaf(epc[c], Lb[b], gpc[c]));
                const float tn = dexp2(fmaf(enc[c], Lb[b], gnc[c]));
                acc[c][b] = fmaf(Sb[b], tp - tn, acc[c][b]);
            }
        }
    }

    // --- epilogue: LDS transpose -> coalesced atomics ---
    __syncthreads();                       // table reads done; reuse B
    float4* S4 = (float4*)B;               // [64 rows][33 float4] = 8448 floats
    #pragma unroll
    for (int b = 0; b < 8; ++b)
        S4[(bt * 8 + b) * 33 + jt] = make_float4(acc[0][b], acc[1][b],
                                                 acc[2][b], acc[3][b]);
    __syncthreads();
    const float* Sf = B;                   // row stride 132 floats
    #pragma unroll
    for (int k = 0; k < 32; ++k) {
        const int idx = tid + k * 256;     // 8192 outputs of this tile
        const int row = idx >> 7;          // batch within tile
        const int col = idx & 127;         // col within tile (lane-contiguous)
        unsafeAtomicAdd(&out[(b0 + row) * NOUT + j0 + col],
                        C * Sf[row * 132 + col]);
    }
}

extern "C" void kernel_launch(void* const* d_in, const int* in_sizes, int n_in,
                              void* d_out, int out_size, void* d_ws, size_t ws_size,
                              hipStream_t stream) {
    const float* x    = (const float*)d_in[0];
    const float* wp   = (const float*)d_in[1];
    const float* wn   = (const float*)d_in[2];
    const float* bp   = (const float*)d_in[3];
    const float* bn   = (const float*)d_in[4];
    const float* npar = (const float*)d_in[5];
    float*        out = (float*)d_out;
    float*         pm = (float*)d_ws;      // 128 partial maxima

    // mk_max zeroes d_out (atomic target) and writes 128 partial maxima
    mk_max<<<128, 256, 0, stream>>>(wp, wn, bp, bn, pm, (float4*)out);

    dim3 grid(NOUT / JTILE, BATCH / BTILE, NZ);
    mk_main<<<grid, 256, 0, stream>>>(x, wp, wn, bp, bn, npar, pm, out);
}